// Round 1
// baseline (297.249 us; speedup 1.0000x reference)
//
#include <hip/hip_runtime.h>
#include <cstddef>

#define H   256
#define L   2048
#define B   32
#define V   50257
#define H2  512
#define H4  1024
#define CH  64                        // flash chunk rows
#define NCH (L/CH)                    // 32 chunks per batch

// output flat offsets (floats)
#define LP_OFF 0
#define HN_OFF (B*V)                 // 1608224
#define CN_OFF (HN_OFF + B*H)        // 1616416
#define AW_OFF (CN_OFF + B*H)        // 1624608

// workspace layout (floats)
#define WS_XL    0                    // 32*512: [h_new | attn_applied]
#define WS_S     (WS_XL + B*H2)       // 32*2048 raw scores
#define WS_AV    (WS_S + B*L)         // 1024*256 chunk partial vectors
#define WS_AM    (WS_AV + B*NCH*H)    // 1024 chunk max
#define WS_AZ    (WS_AM + B*NCH)      // 1024 chunk sumexp
#define WS_PM    (WS_AZ + B*NCH)      // 32*400 lsm per-block max
#define WS_PZ    (WS_PM + 12800)      // 32*400 lsm per-block sumexp

#define NBLK_LOG 393                  // ceil(V/128)

typedef __attribute__((ext_vector_type(8))) short bf16x8;
typedef __attribute__((ext_vector_type(4))) float f32x4;

__device__ inline unsigned short f2bf(float f) {
    unsigned u = __builtin_bit_cast(unsigned, f);
    u += 0x7FFFu + ((u >> 16) & 1u);          // RNE to bf16
    return (unsigned short)(u >> 16);
}

// ---------------------------------------------------------------- flash attention:
// block = (b, chunk of 64 l).  Computes w = v^T We in-block (W_attn cols L2-hot),
// then scores with k-split-16, chunk softmax partial, weighted vector partial.
__global__ __launch_bounds__(256) void k_attn(const float* __restrict__ W_attn,
                                              const float* __restrict__ v,
                                              const float* __restrict__ enc,
                                              float* __restrict__ ws) {
    int bid = blockIdx.x;             // b*NCH + chunk
    int b = bid >> 5, chunk = bid & (NCH - 1);
    int t = threadIdx.x;
    int wave = t >> 6, lane = t & 63;
    int g = lane >> 4, u = lane & 15;
    __shared__ float v_s[H];
    __shared__ float w_s[H];
    __shared__ float s_lds[CH];
    __shared__ float p_lds[CH];
    __shared__ float red[CH];
    __shared__ float vec_lds[4][256];

    // w[t] = sum_k v[k] * W_attn[k, H+t]   (256 KB of W_attn, L2-resident)
    v_s[t] = v[t];
    __syncthreads();
    {
        const float* base = W_attn + H + t;
        float wa = 0.f, wb = 0.f;
        #pragma unroll 8
        for (int k = 0; k < H; k += 2) {
            wa += v_s[k]     * base[(size_t)k * H2];
            wb += v_s[k + 1] * base[(size_t)(k + 1) * H2];
        }
        w_s[t] = wa + wb;
    }
    __syncthreads();

    size_t rowbase = (size_t)b * L + chunk * CH;
    const float4* w4s = (const float4*)w_s;
    float4 w0 = w4s[u], w1 = w4s[16 + u], w2 = w4s[32 + u], w3 = w4s[48 + u];

    // phase 1: scores.  wave handles rows [wave*16, wave*16+16), 4 at a time (one per g);
    // 16 lanes (u) split k, 4 independent float4 loads per lane per row.
    #pragma unroll
    for (int ir = 0; ir < 4; ir++) {
        int rl = wave * 16 + ir * 4 + g;
        const float4* e4 = (const float4*)(enc + (rowbase + rl) * H);
        float4 a0 = e4[u], a1 = e4[16 + u], a2 = e4[32 + u], a3 = e4[48 + u];
        float p = a0.x * w0.x + a0.y * w0.y + a0.z * w0.z + a0.w * w0.w
                + a1.x * w1.x + a1.y * w1.y + a1.z * w1.z + a1.w * w1.w
                + a2.x * w2.x + a2.y * w2.y + a2.z * w2.z + a2.w * w2.w
                + a3.x * w3.x + a3.y * w3.y + a3.z * w3.z + a3.w * w3.w;
        p += __shfl_down(p, 8); p += __shfl_down(p, 4);
        p += __shfl_down(p, 2); p += __shfl_down(p, 1);
        if (u == 0) s_lds[rl] = p;
    }
    __syncthreads();

    // chunk softmax partial over 64 rows
    if (t < CH) red[t] = s_lds[t];
    __syncthreads();
    for (int off = 32; off; off >>= 1) { if (t < off) red[t] = fmaxf(red[t], red[t + off]); __syncthreads(); }
    float m = red[0];
    __syncthreads();
    if (t < CH) {
        float e = __expf(s_lds[t] - m);
        p_lds[t] = e; red[t] = e;
        ws[WS_S + rowbase + t] = s_lds[t];
    }
    __syncthreads();
    for (int off = 32; off; off >>= 1) { if (t < off) red[t] += red[t + off]; __syncthreads(); }

    // phase 2: weighted vector partial; wave w covers rows [w*16, w*16+16), lane = h float4
    float4 acc = make_float4(0.f, 0.f, 0.f, 0.f);
    const float4* ebase = (const float4*)(enc + (rowbase + wave * 16) * H);
    #pragma unroll 4
    for (int i = 0; i < 16; i++) {
        float p = p_lds[wave * 16 + i];
        float4 a = ebase[i * 64 + lane];
        acc.x += p * a.x; acc.y += p * a.y; acc.z += p * a.z; acc.w += p * a.w;
    }
    *(float4*)&vec_lds[wave][lane * 4] = acc;
    __syncthreads();
    ws[WS_AV + (size_t)bid * 256 + t] = vec_lds[0][t] + vec_lds[1][t] + vec_lds[2][t] + vec_lds[3][t];
    if (t == 0) { ws[WS_AM + bid] = m; ws[WS_AZ + bid] = red[0]; }
}

// ---------------------------------------------------------------- fused comb + gates + lstm:
// block = (b, s) with s = 16-row t-slice (16 slices per b -> 512 blocks).
// Phase A: combine chunk partials -> attn_applied (redundant per slice, L2-hot);
//          x = [emb | attn] and h staged in LDS; s==0 writes attn_weights + XL attn half.
// Phase B: 64 gate rows (4 gates x 16) computed wave-per-row, x/h from registers.
// Phase C: LSTM pointwise for the 16 t's; writes h_new/c_new outputs + XL h slice.
__global__ __launch_bounds__(256) void k_fuse(const int* __restrict__ tokens,
                                              const float* __restrict__ emb,
                                              const float* __restrict__ hidden,
                                              const float* __restrict__ cell,
                                              const float* __restrict__ W_ih,
                                              const float* __restrict__ b_ih,
                                              const float* __restrict__ W_hh,
                                              const float* __restrict__ b_hh,
                                              float* __restrict__ ws,
                                              float* __restrict__ out) {
    int blk = blockIdx.x;
    int b = blk >> 4, s = blk & 15;
    int t = threadIdx.x;
    int wave = t >> 6, lane = t & 63;
    __shared__ float mc[NCH], zc[NCH];
    __shared__ float xs[H2];          // [embedded | attn_applied]
    __shared__ float hs[H];
    __shared__ float gl[64];          // gate results: [gate][16]

    if (t < NCH) { mc[t] = ws[WS_AM + b * NCH + t]; zc[t] = ws[WS_AZ + b * NCH + t]; }
    hs[t] = hidden[(size_t)b * H + t];
    int tok = tokens[b];
    xs[t] = emb[(size_t)tok * H + t];
    __syncthreads();

    // phase A: global softmax stats + weighted combine of chunk vectors
    float M = -1e30f;
    #pragma unroll
    for (int c = 0; c < NCH; c++) M = fmaxf(M, mc[c]);
    float Z = 0.f;
    #pragma unroll
    for (int c = 0; c < NCH; c++) Z += zc[c] * __expf(mc[c] - M);
    float inv = 1.f / Z;
    float acc = 0.f;
    #pragma unroll 8
    for (int c = 0; c < NCH; c++) acc += __expf(mc[c] - M) * ws[WS_AV + (size_t)(b * NCH + c) * H + t];
    acc *= inv;
    xs[H + t] = acc;
    if (s == 0) {
        ws[WS_XL + b * H2 + H + t] = acc;
        #pragma unroll
        for (int j = 0; j < 8; j++) {
            int l = t + 256 * j;
            out[AW_OFF + (size_t)b * L + l] = __expf(ws[WS_S + (size_t)b * L + l] - M) * inv;
        }
    }
    __syncthreads();

    // phase B: gates.  wave = gate index; 16 rows per wave; k split over 64 lanes.
    int ts = s * 16;
    const float4* xs4 = (const float4*)xs;
    const float4* hs4 = (const float4*)hs;
    float4 x0 = xs4[lane * 2], x1 = xs4[lane * 2 + 1];
    float4 xh = hs4[lane];
    for (int it = 0; it < 16; it++) {
        int j = (wave << 8) + ts + it;                     // gate row in [0,1024)
        const float4* wi = (const float4*)(W_ih + (size_t)j * H2);
        float4 a0 = wi[lane * 2], a1 = wi[lane * 2 + 1];
        const float4* wh = (const float4*)(W_hh + (size_t)j * H);
        float4 a2 = wh[lane];
        float p = a0.x * x0.x + a0.y * x0.y + a0.z * x0.z + a0.w * x0.w
                + a1.x * x1.x + a1.y * x1.y + a1.z * x1.z + a1.w * x1.w
                + a2.x * xh.x + a2.y * xh.y + a2.z * xh.z + a2.w * xh.w;
        #pragma unroll
        for (int off = 32; off; off >>= 1) p += __shfl_down(p, off);
        if (lane == 0) gl[wave * 16 + it] = p + b_ih[j] + b_hh[j];
    }
    __syncthreads();

    // phase C: LSTM pointwise for this block's 16 t's
    if (t < 16) {
        int tt = ts + t;
        float ig = gl[t], fg = gl[16 + t], gg = gl[32 + t], og = gl[48 + t];
        float c = cell[(size_t)b * H + tt];
        float si = 1.f / (1.f + expf(-ig));
        float sf = 1.f / (1.f + expf(-fg));
        float so = 1.f / (1.f + expf(-og));
        float cn = sf * c + si * tanhf(gg);
        float hn = so * tanhf(cn);
        out[HN_OFF + b * H + tt] = hn;
        out[CN_OFF + b * H + tt] = cn;
        ws[WS_XL + b * H2 + tt] = hn;
    }
}

// ---------------------------------------------------------------- logits (bf16 MFMA):
// C[b,r] = X[b,:].W_out[r,:] + b_out[r].  Block = 128 rows; wave = 32 rows (2 strips
// of 16) x 32 batches (2 n-tiles of 16).  Rows clamped (branch-free K loop).
__global__ __launch_bounds__(256) void k_logits(const float* __restrict__ W_out,
                                                const float* __restrict__ b_out,
                                                float* __restrict__ ws,
                                                float* __restrict__ out) {
    __shared__ unsigned short Xl[32 * 520];   // 33,280 B
    int t = threadIdx.x;
    const float4* xl4 = (const float4*)(ws + WS_XL);
    #pragma unroll
    for (int it = 0; it < 16; it++) {
        int fi = t + 256 * it;                // float4 index over 32x128
        int b = fi >> 7, kq = fi & 127;
        float4 xv = xl4[b * 128 + kq];
        unsigned p0 = (unsigned)f2bf(xv.x) | ((unsigned)f2bf(xv.y) << 16);
        unsigned p1 = (unsigned)f2bf(xv.z) | ((unsigned)f2bf(xv.w) << 16);
        unsigned* dst = (unsigned*)&Xl[b * 520 + kq * 4];
        dst[0] = p0; dst[1] = p1;
    }
    __syncthreads();

    int wave = t >> 6, lane = t & 63, quad = lane >> 4, m = lane & 15;
    int rbase = blockIdx.x * 128 + wave * 32;
    f32x4 zero4 = {0.f, 0.f, 0.f, 0.f};
    f32x4 acc[2][2];
    acc[0][0] = zero4; acc[0][1] = zero4; acc[1][0] = zero4; acc[1][1] = zero4;

    int r0 = rbase + m;
    int r1 = rbase + 16 + m;
    int r0c = r0 < V ? r0 : V - 1;
    int r1c = r1 < V ? r1 : V - 1;
    const float* wp0 = W_out + (size_t)r0c * H2 + quad * 8;
    const float* wp1 = W_out + (size_t)r1c * H2 + quad * 8;

    for (int kp = 0; kp < 16; kp++) {
        int k0 = kp * 32;
        float4 lo0 = *(const float4*)(wp0 + k0);
        float4 hi0 = *(const float4*)(wp0 + k0 + 4);
        float4 lo1 = *(const float4*)(wp1 + k0);
        float4 hi1 = *(const float4*)(wp1 + k0 + 4);
        bf16x8 a0, a1;
        a0[0]=(short)f2bf(lo0.x); a0[1]=(short)f2bf(lo0.y); a0[2]=(short)f2bf(lo0.z); a0[3]=(short)f2bf(lo0.w);
        a0[4]=(short)f2bf(hi0.x); a0[5]=(short)f2bf(hi0.y); a0[6]=(short)f2bf(hi0.z); a0[7]=(short)f2bf(hi0.w);
        a1[0]=(short)f2bf(lo1.x); a1[1]=(short)f2bf(lo1.y); a1[2]=(short)f2bf(lo1.z); a1[3]=(short)f2bf(lo1.w);
        a1[4]=(short)f2bf(hi1.x); a1[5]=(short)f2bf(hi1.y); a1[6]=(short)f2bf(hi1.z); a1[7]=(short)f2bf(hi1.w);
        bf16x8 b0 = *(bf16x8*)&Xl[(size_t)m * 520 + k0 + quad * 8];
        bf16x8 b1 = *(bf16x8*)&Xl[(size_t)(16 + m) * 520 + k0 + quad * 8];
        acc[0][0] = __builtin_amdgcn_mfma_f32_16x16x32_bf16(a0, b0, acc[0][0], 0, 0, 0);
        acc[0][1] = __builtin_amdgcn_mfma_f32_16x16x32_bf16(a0, b1, acc[0][1], 0, 0, 0);
        acc[1][0] = __builtin_amdgcn_mfma_f32_16x16x32_bf16(a1, b0, acc[1][0], 0, 0, 0);
        acc[1][1] = __builtin_amdgcn_mfma_f32_16x16x32_bf16(a1, b1, acc[1][1], 0, 0, 0);
    }

    // epilogue: bias, store, per-wave softmax partials
    float val[2][2][4];
    #pragma unroll
    for (int s = 0; s < 2; s++) {
        #pragma unroll
        for (int i = 0; i < 4; i++) {
            int rr = rbase + s * 16 + quad * 4 + i;
            float bo = (rr < V) ? b_out[rr] : 0.f;
            #pragma unroll
            for (int nt = 0; nt < 2; nt++) {
                float vv = acc[s][nt][i] + bo;
                if (rr < V) {
                    int bcol = nt * 16 + m;
                    out[(size_t)bcol * V + rr] = vv;
                    val[s][nt][i] = vv;
                } else {
                    val[s][nt][i] = -1e30f;
                }
            }
        }
    }
    float pm[2], pz[2];
    #pragma unroll
    for (int nt = 0; nt < 2; nt++) {
        float mx = -1e30f;
        #pragma unroll
        for (int s = 0; s < 2; s++)
            #pragma unroll
            for (int i = 0; i < 4; i++) mx = fmaxf(mx, val[s][nt][i]);
        float sm = 0.f;
        #pragma unroll
        for (int s = 0; s < 2; s++)
            #pragma unroll
            for (int i = 0; i < 4; i++) sm += __expf(val[s][nt][i] - mx);
        pm[nt] = mx; pz[nt] = sm;
    }
    #pragma unroll
    for (int off = 16; off <= 32; off <<= 1) {
        #pragma unroll
        for (int nt = 0; nt < 2; nt++) {
            float om = __shfl_xor(pm[nt], off);
            float oz = __shfl_xor(pz[nt], off);
            float nm = fmaxf(pm[nt], om);
            pz[nt] = pz[nt] * __expf(pm[nt] - nm) + oz * __expf(om - nm);
            pm[nt] = nm;
        }
    }
    __syncthreads();
    float* red = (float*)Xl;
    if (quad == 0) {
        #pragma unroll
        for (int nt = 0; nt < 2; nt++) {
            red[wave * 32 + nt * 16 + m]       = pm[nt];
            red[128 + wave * 32 + nt * 16 + m] = pz[nt];
        }
    }
    __syncthreads();
    if (t < 32) {
        float mf = -1e30f;
        #pragma unroll
        for (int w = 0; w < 4; w++) mf = fmaxf(mf, red[w * 32 + t]);
        float z = 0.f;
        #pragma unroll
        for (int w = 0; w < 4; w++) z += red[128 + w * 32 + t] * __expf(red[w * 32 + t] - mf);
        ws[WS_PM + t * 400 + blockIdx.x] = mf;
        ws[WS_PZ + t * 400 + blockIdx.x] = z;
    }
}

// ---------------------------------------------------------------- log-softmax finalize:
// block = (1024-logit tile, b).  Combines the 393 per-block partials in-block
// (3 KB, L2-hot, identical result across blocks of same b), then subtracts.
__global__ __launch_bounds__(256) void k_lsm_final(const float* __restrict__ ws,
                                                   float* __restrict__ out) {
    int b = blockIdx.y, t = threadIdx.x;
    __shared__ float rm[256], rz[256];
    float m = -1e30f, z = 0.f;
    for (int i = t; i < NBLK_LOG; i += 256) {
        float mi = ws[WS_PM + b * 400 + i];
        float zi = ws[WS_PZ + b * 400 + i];
        float nm = fmaxf(m, mi);
        z = z * __expf(m - nm) + zi * __expf(mi - nm);
        m = nm;
    }
    rm[t] = m; rz[t] = z; __syncthreads();
    for (int off = 128; off; off >>= 1) {
        if (t < off) {
            float m2 = rm[t + off], z2 = rz[t + off];
            float nm = fmaxf(rm[t], m2);
            rz[t] = rz[t] * __expf(rm[t] - nm) + z2 * __expf(m2 - nm);
            rm[t] = nm;
        }
        __syncthreads();
    }
    float M = rm[0], LZ = logf(rz[0]);
    int rbase = blockIdx.x * 1024 + t;
    #pragma unroll
    for (int j = 0; j < 4; j++) {
        int r = rbase + 256 * j;
        if (r < V) {
            size_t i = (size_t)b * V + r;
            out[i] = out[i] - M - LZ;
        }
    }
}

extern "C" void kernel_launch(void* const* d_in, const int* in_sizes, int n_in,
                              void* d_out, int out_size, void* d_ws, size_t ws_size,
                              hipStream_t stream) {
    const int*   tokens = (const int*)d_in[0];
    const float* hidden = (const float*)d_in[1];
    const float* cell   = (const float*)d_in[2];
    const float* enc    = (const float*)d_in[3];
    const float* emb    = (const float*)d_in[4];
    const float* W_attn = (const float*)d_in[5];
    const float* v      = (const float*)d_in[7];
    const float* W_ih   = (const float*)d_in[8];
    const float* b_ih   = (const float*)d_in[9];
    const float* W_hh   = (const float*)d_in[10];
    const float* b_hh   = (const float*)d_in[11];
    const float* W_out  = (const float*)d_in[12];
    const float* b_out  = (const float*)d_in[13];
    float* out = (float*)d_out;
    float* ws  = (float*)d_ws;

    k_attn<<<B * NCH, 256, 0, stream>>>(W_attn, v, enc, ws);
    k_fuse<<<B * 16, 256, 0, stream>>>(tokens, emb, hidden, cell, W_ih, b_ih, W_hh, b_hh, ws, out);
    k_logits<<<NBLK_LOG, 256, 0, stream>>>(W_out, b_out, ws, out);
    k_lsm_final<<<dim3((V + 1023) / 1024, B), 256, 0, stream>>>(ws, out);
}